// Round 8
// baseline (194.516 us; speedup 1.0000x reference)
//
#include <hip/hip_runtime.h>

typedef unsigned short bfu;
typedef __attribute__((ext_vector_type(8))) short short8;
typedef __attribute__((ext_vector_type(4))) float f32x4;

__device__ __forceinline__ float bf2f(bfu u){
  union { unsigned int i; float f; } v; v.i = ((unsigned int)u) << 16; return v.f;
}
__device__ __forceinline__ bfu f2bf(float f){
  union { float f; unsigned int i; } v; v.f = f;
  unsigned int r = (v.i + 0x7FFFu + ((v.i >> 16) & 1u)) >> 16;
  return (bfu)r;
}
__device__ __forceinline__ float fexp2(float x){ return __builtin_amdgcn_exp2f(x); }
__device__ __forceinline__ float flog2(float x){ return __builtin_amdgcn_logf(x); }
__device__ __forceinline__ float softplusf(float x){
  float t = fexp2(-fabsf(x) * 1.44269504088896f);
  return fmaxf(x, 0.f) + 0.69314718055995f * flog2(1.f + t);
}
__device__ __forceinline__ void gload16(const bfu* g, bfu* l){
  __builtin_amdgcn_global_load_lds((const __attribute__((address_space(1))) unsigned int*)g,
                                   (__attribute__((address_space(3))) unsigned int*)l, 16, 0, 0);
}

// ---------------- fused conversion kernel ----------------
__global__ __launch_bounds__(256) void cvt_all_kernel(const float* __restrict__ x, bfu* __restrict__ x_bf,
                                                      const float* __restrict__ W_in, const float* __restrict__ W_out,
                                                      const float* __restrict__ W_x,
                                                      bfu* __restrict__ WinT, bfu* __restrict__ WoutT,
                                                      float* __restrict__ WxT){
  int g = blockIdx.x * 256 + threadIdx.x;
  if (g < 2097152){
    float4 v = ((const float4*)x)[g];
    ushort4 o;
    o.x = f2bf(v.x); o.y = f2bf(v.y); o.z = f2bf(v.z); o.w = f2bf(v.w);
    ((ushort4*)x_bf)[g] = o;
    return;
  }
  int h = g - 2097152;
  if (h < 786432){
    int r = h % 512, c = h / 512;
    WinT[h] = f2bf(W_in[(size_t)r * 1536 + c]);
  } else if (h < 786432 + 393216){
    int h2 = h - 786432;
    int r = h2 % 768, c = h2 / 768;
    WoutT[h2] = f2bf(W_out[(size_t)r * 512 + c]);
  } else if (h < 786432 + 393216 + 6144){
    int h2 = h - (786432 + 393216);
    int n = h2 / 768, k = h2 % 768;
    WxT[h2] = W_x[(size_t)k * 8 + n];
  }
}

// ---------------- MFMA GEMM, fine-interleaved phase template ----------------
// C = A(MxK) * Bt(NxK)^T.  BM=256, BN=128, BK=32.  256 threads = 4 waves
// (2M x 2N), per-wave 128x64 output (acc[8][4] 16x16 frags).
// LDS: 3 bufs x (A 256x32 + B 128x32) bf16 = 3 x 24KB = 72KB -> 2 blocks/CU.
// Per K-tile: 2 phases, each {ds_read subtile || stage 1 unit of tile t+2
//   -> s_barrier -> setprio(1) 16 MFMA setprio(0) -> s_barrier}.
// Boundary s_waitcnt vmcnt(6): tile t+1 landed, t+2's 6 loads stay in flight.
// T1 XCD swizzle; T2 LDS swizzle slot=(logical+row/2)&3 on BOTH sides; T5.
template<int EPI, int KK>
__global__ __launch_bounds__(256)
void gemm_8p(const bfu* __restrict__ Amat, const bfu* __restrict__ Bt,
             void* __restrict__ out0, void* __restrict__ out1,
             int NBN, int N)
{
  constexpr int NT = KK / 32;
  __shared__ bfu LDS[3 * 12288];
  const int tid  = threadIdx.x;
  const int lane = tid & 63;
  const int w    = tid >> 6;
  const int wr   = w >> 1, wc = w & 1;   // 2 x 2 wave grid, 128x64 each

  // T1: XCD-aware bijective swizzle (grid % 8 == 0)
  const int cpx = gridDim.x >> 3;
  const int id  = blockIdx.x;
  const int nid = (id & 7) * cpx + (id >> 3);
  const int bn  = nid % NBN;
  const int bm  = nid / NBN;

  // ---- staging addressing (T2 pre-swizzled global source, linear LDS dest)
  // set of 64 rows: thread t -> row (t>>2), dest slot t&3;
  // dest slot S at row r holds logical slot (S - (r>>1)) & 3
  const int grow  = tid >> 2;                              // 0..63
  const int gslot = ((tid & 3) - ((tid >> 3) & 3)) & 3;    // logical col slot
  const bfu* gA = Amat + ((size_t)(bm * 256 + grow)) * KK + gslot * 8;
  const bfu* gB = Bt   + ((size_t)(bn * 128 + grow)) * KK + gslot * 8;

  auto STAGE_A = [&](int t, int buf){                      // 4 gloads (16KB)
    const int k0 = t * 32;
    bfu* dst = (bfu*)LDS + buf * 12288 + tid * 8;
    #pragma unroll
    for (int i = 0; i < 4; i++)
      gload16(gA + (size_t)(i * 64) * KK + k0, dst + i * 2048);
  };
  auto STAGE_B = [&](int t, int buf){                      // 2 gloads (8KB)
    const int k0 = t * 32;
    bfu* dst = (bfu*)LDS + buf * 12288 + 8192 + tid * 8;
    #pragma unroll
    for (int j = 0; j < 2; j++)
      gload16(gB + (size_t)(j * 64) * KK + k0, dst + j * 2048);
  };

  // ---- read-side fragment addressing (swizzled slot; lane-only, row-invariant)
  const int rslot = (((lane >> 4) + ((lane & 15) >> 1)) & 3) * 8;
  const int aoff  = (wr * 128 + (lane & 15)) * 32 + rslot;          // + m*512
  const int boff  = 8192 + (wc * 64 + (lane & 15)) * 32 + rslot;    // + n*512

  f32x4 acc[8][4];
  #pragma unroll
  for (int i = 0; i < 8; i++)
    #pragma unroll
    for (int j = 0; j < 4; j++)
      #pragma unroll
      for (int r = 0; r < 4; r++) acc[i][j][r] = 0.f;

  // prologue: tiles 0 and 1 in flight; wait tile 0 (6 younger stay out)
  STAGE_A(0, 0); STAGE_B(0, 0);
  STAGE_A(1, 1); STAGE_B(1, 1);
  asm volatile("s_waitcnt vmcnt(6)" ::: "memory");
  __builtin_amdgcn_s_barrier();

  int cur = 0, s2 = 2;
  for (int t = 0; t < NT; ++t){
    const bfu* Lb = (const bfu*)LDS + cur * 12288;
    short8 a0, a1, a2, a3, b0, b1, b2, b3;

    // ---- phase 1: read Q0 subtile, stage A-unit of t+2, MFMA m-half 0
    a0 = *(const short8*)&Lb[aoff + 0 * 512];
    a1 = *(const short8*)&Lb[aoff + 1 * 512];
    a2 = *(const short8*)&Lb[aoff + 2 * 512];
    a3 = *(const short8*)&Lb[aoff + 3 * 512];
    b0 = *(const short8*)&Lb[boff + 0 * 512];
    b1 = *(const short8*)&Lb[boff + 1 * 512];
    b2 = *(const short8*)&Lb[boff + 2 * 512];
    b3 = *(const short8*)&Lb[boff + 3 * 512];
    if (t + 2 < NT) STAGE_A(t + 2, s2);
    __builtin_amdgcn_s_barrier();
    __builtin_amdgcn_s_setprio(1);
    #pragma unroll
    for (int mi = 0; mi < 4; mi++){
      const short8 am = (mi == 0) ? a0 : (mi == 1) ? a1 : (mi == 2) ? a2 : a3;
      acc[mi][0] = __builtin_amdgcn_mfma_f32_16x16x32_bf16(am, b0, acc[mi][0], 0, 0, 0);
      acc[mi][1] = __builtin_amdgcn_mfma_f32_16x16x32_bf16(am, b1, acc[mi][1], 0, 0, 0);
      acc[mi][2] = __builtin_amdgcn_mfma_f32_16x16x32_bf16(am, b2, acc[mi][2], 0, 0, 0);
      acc[mi][3] = __builtin_amdgcn_mfma_f32_16x16x32_bf16(am, b3, acc[mi][3], 0, 0, 0);
    }
    __builtin_amdgcn_s_setprio(0);
    __builtin_amdgcn_s_barrier();

    // ---- phase 2: read Q1 subtile, stage B-unit of t+2, MFMA m-half 1
    a0 = *(const short8*)&Lb[aoff + 4 * 512];
    a1 = *(const short8*)&Lb[aoff + 5 * 512];
    a2 = *(const short8*)&Lb[aoff + 6 * 512];
    a3 = *(const short8*)&Lb[aoff + 7 * 512];
    if (t + 2 < NT) STAGE_B(t + 2, s2);
    __builtin_amdgcn_s_barrier();
    __builtin_amdgcn_s_setprio(1);
    #pragma unroll
    for (int mi = 0; mi < 4; mi++){
      const short8 am = (mi == 0) ? a0 : (mi == 1) ? a1 : (mi == 2) ? a2 : a3;
      acc[4 + mi][0] = __builtin_amdgcn_mfma_f32_16x16x32_bf16(am, b0, acc[4 + mi][0], 0, 0, 0);
      acc[4 + mi][1] = __builtin_amdgcn_mfma_f32_16x16x32_bf16(am, b1, acc[4 + mi][1], 0, 0, 0);
      acc[4 + mi][2] = __builtin_amdgcn_mfma_f32_16x16x32_bf16(am, b2, acc[4 + mi][2], 0, 0, 0);
      acc[4 + mi][3] = __builtin_amdgcn_mfma_f32_16x16x32_bf16(am, b3, acc[4 + mi][3], 0, 0, 0);
    }
    __builtin_amdgcn_s_setprio(0);
    __builtin_amdgcn_s_barrier();

    // ---- K-tile boundary: ensure tile t+1 resident; keep t+2 in flight
    if (t < NT - 2)       asm volatile("s_waitcnt vmcnt(6)" ::: "memory");
    else if (t == NT - 2) asm volatile("s_waitcnt vmcnt(0)" ::: "memory");
    cur = (cur == 2) ? 0 : cur + 1;
    s2  = (s2  == 2) ? 0 : s2  + 1;
  }

  // ---- epilogue
  #pragma unroll
  for (int m = 0; m < 8; m++){
    #pragma unroll
    for (int n = 0; n < 4; n++){
      const int row0 = bm * 256 + wr * 128 + m * 16 + (lane >> 4) * 4;
      const int col  = bn * 128 + wc * 64 + n * 16 + (lane & 15);
      #pragma unroll
      for (int r = 0; r < 4; r++){
        float v = acc[m][n][r];
        int row = row0 + r;
        if (EPI == 0){
          float s = v / (1.f + __expf(-v));   // silu
          if (col < 768) ((bfu*)out0)[(size_t)row * 768 + col]         = f2bf(s);
          else           ((bfu*)out1)[(size_t)row * 768 + (col - 768)] = f2bf(s);
        } else {
          ((float*)out0)[(size_t)row * N + col] = v;
        }
      }
    }
  }
}

// ---------------- u = xssm @ W_x  (uses WxT [8][768], coalesced) ----------------
__global__ __launch_bounds__(256) void u_kernel(const bfu* __restrict__ xssm, const float* __restrict__ WxT,
                                                float* __restrict__ u){
  int wid = threadIdx.x >> 6, lane = threadIdx.x & 63;
  int row = blockIdx.x * 4 + wid;
  const bfu* xr = xssm + (size_t)row * 768;
  float acc[8];
  #pragma unroll
  for (int n = 0; n < 8; n++) acc[n] = 0.f;
  #pragma unroll
  for (int i = 0; i < 3; i++){
    int kb = i * 256 + lane * 4;
    ushort4 xq = *(const ushort4*)(xr + kb);
    float x0 = bf2f(xq.x), x1 = bf2f(xq.y), x2 = bf2f(xq.z), x3 = bf2f(xq.w);
    #pragma unroll
    for (int n = 0; n < 8; n++){
      float4 wv = *(const float4*)(WxT + (size_t)n * 768 + kb);
      acc[n] += x0 * wv.x + x1 * wv.y + x2 * wv.z + x3 * wv.w;
    }
  }
  #pragma unroll
  for (int n = 0; n < 8; n++){
    #pragma unroll
    for (int off = 32; off >= 1; off >>= 1) acc[n] += __shfl_xor(acc[n], off, 64);
  }
  if (lane == 0){
    float4 o0 = { acc[0], acc[1], acc[2], acc[3] };
    float4 o1 = { acc[4], acc[5], acc[6], acc[7] };
    *(float4*)(u + (size_t)row * 8)     = o0;
    *(float4*)(u + (size_t)row * 8 + 4) = o1;
  }
}

// ---------------- scan phase 1: per-chunk local scan, delta inline ----------------
__global__ __launch_bounds__(128) void scan_phase1(const bfu* __restrict__ xssm, const float* __restrict__ u,
    const float* __restrict__ Wdt, const float* __restrict__ bdt, const float* __restrict__ A_log,
    float* __restrict__ Pws, float* __restrict__ Hws){
  int tid = threadIdx.x;
  int bid = blockIdx.x;
  int b = bid / 192; int rem = bid % 192;
  int c = rem / 3;   int dblk = rem % 3;
  int d0 = dblk * 256 + tid * 2;
  float Al2[2][8], H[2][8], Wr[2][8], bd[2], S[2];
  #pragma unroll
  for (int j = 0; j < 2; j++){
    bd[j] = bdt[d0 + j];
    S[j] = 0.f;
    #pragma unroll
    for (int n = 0; n < 8; n++){
      Al2[j][n] = -__expf(A_log[(size_t)(d0 + j) * 8 + n]) * 1.4426950408889634f;
      Wr[j][n]  = Wdt[(size_t)n * 768 + d0 + j];
      H[j][n] = 0.f;
    }
  }
  int r0 = b * 2048 + c * 32;
  size_t base = (size_t)r0 * 768 + d0;
  #pragma unroll 8
  for (int i = 0; i < 32; i++){
    float4 u0 = *(const float4*)(u + (size_t)(r0 + i) * 8);
    float4 u1 = *(const float4*)(u + (size_t)(r0 + i) * 8 + 4);
    ushort2 xq = *(const ushort2*)(xssm + base + (size_t)i * 768);
    #pragma unroll
    for (int j = 0; j < 2; j++){
      float xt = bf2f(j == 0 ? xq.x : xq.y);
      float dv = bd[j] + u0.x * Wr[j][0] + u0.y * Wr[j][1] + u0.z * Wr[j][2] + u0.w * Wr[j][3]
                       + u1.x * Wr[j][4] + u1.y * Wr[j][5] + u1.z * Wr[j][6] + u1.w * Wr[j][7];
      float dt = softplusf(dv);
      float dx = dt * xt;
      S[j] += dt;
      #pragma unroll
      for (int n = 0; n < 8; n++){
        float e = fexp2(dt * Al2[j][n]);
        H[j][n] = e * H[j][n] + dx;
      }
    }
  }
  size_t o = (((size_t)b * 64 + c) * 768 + d0) * 8;
  #pragma unroll
  for (int j = 0; j < 2; j++){
    float4 p0, p1;
    p0.x = fexp2(S[j] * Al2[j][0]); p0.y = fexp2(S[j] * Al2[j][1]);
    p0.z = fexp2(S[j] * Al2[j][2]); p0.w = fexp2(S[j] * Al2[j][3]);
    p1.x = fexp2(S[j] * Al2[j][4]); p1.y = fexp2(S[j] * Al2[j][5]);
    p1.z = fexp2(S[j] * Al2[j][6]); p1.w = fexp2(S[j] * Al2[j][7]);
    float4 h0 = { H[j][0], H[j][1], H[j][2], H[j][3] };
    float4 h1 = { H[j][4], H[j][5], H[j][6], H[j][7] };
    *(float4*)(Pws + o + j * 8)     = p0;
    *(float4*)(Pws + o + j * 8 + 4) = p1;
    *(float4*)(Hws + o + j * 8)     = h0;
    *(float4*)(Hws + o + j * 8 + 4) = h1;
  }
}

// ---------------- scan phase 2: combine chunks; Hin written IN-PLACE into Pws ----------------
__global__ __launch_bounds__(256) void scan_phase2(float* __restrict__ Pws, const float* __restrict__ Hws){
  int g = blockIdx.x * 256 + threadIdx.x;   // 49152 = 8*768*8
  int within = g % 6144;                    // d*8+n
  int b = g / 6144;
  size_t base = (size_t)b * 64 * 6144 + within;
  float hin = 0.f;
  #pragma unroll 8
  for (int c = 0; c < 64; c++){
    size_t idx = base + (size_t)c * 6144;
    float p = Pws[idx], hh = Hws[idx];
    Pws[idx] = hin;                         // h_in for chunk c
    hin = p * hin + hh;
  }
}

// ---------------- scan phase 3: re-run chunk with h_in, delta inline, fuse gate ----------------
__global__ __launch_bounds__(128) void scan_phase3(const bfu* __restrict__ xssm, const float* __restrict__ u,
    const float* __restrict__ Wdt, const float* __restrict__ bdt, const float* __restrict__ A_log,
    const float* __restrict__ Dp, const bfu* __restrict__ siluz, const float* __restrict__ Hin,
    bfu* __restrict__ yz){
  int tid = threadIdx.x;
  int bid = blockIdx.x;
  int b = bid / 192; int rem = bid % 192;
  int c = rem / 3;   int dblk = rem % 3;
  int d0 = dblk * 256 + tid * 2;
  float Al2[2][8], H[2][8], Wr[2][8], bd[2], Dd[2];
  size_t o = (((size_t)b * 64 + c) * 768 + d0) * 8;
  #pragma unroll
  for (int j = 0; j < 2; j++){
    bd[j] = bdt[d0 + j];
    Dd[j] = Dp[d0 + j];
    float4 h0 = *(const float4*)(Hin + o + j * 8);
    float4 h1 = *(const float4*)(Hin + o + j * 8 + 4);
    H[j][0] = h0.x; H[j][1] = h0.y; H[j][2] = h0.z; H[j][3] = h0.w;
    H[j][4] = h1.x; H[j][5] = h1.y; H[j][6] = h1.z; H[j][7] = h1.w;
    #pragma unroll
    for (int n = 0; n < 8; n++){
      Al2[j][n] = -__expf(A_log[(size_t)(d0 + j) * 8 + n]) * 1.4426950408889634f;
      Wr[j][n]  = Wdt[(size_t)n * 768 + d0 + j];
    }
  }
  int r0 = b * 2048 + c * 32;
  size_t base = (size_t)r0 * 768 + d0;
  #pragma unroll 8
  for (int i = 0; i < 32; i++){
    float4 u0 = *(const float4*)(u + (size_t)(r0 + i) * 8);
    float4 u1 = *(const float4*)(u + (size_t)(r0 + i) * 8 + 4);
    ushort2 xq = *(const ushort2*)(xssm + base + (size_t)i * 768);
    ushort2 zq = *(const ushort2*)(siluz + base + (size_t)i * 768);
    ushort2 oq;
    #pragma unroll
    for (int j = 0; j < 2; j++){
      float xt = bf2f(j == 0 ? xq.x : xq.y);
      float dv = bd[j] + u0.x * Wr[j][0] + u0.y * Wr[j][1] + u0.z * Wr[j][2] + u0.w * Wr[j][3]
                       + u1.x * Wr[j][4] + u1.y * Wr[j][5] + u1.z * Wr[j][6] + u1.w * Wr[j][7];
      float dt = softplusf(dv);
      float dx = dt * xt;
      float y = Dd[j] * xt;
      #pragma unroll
      for (int n = 0; n < 8; n++){
        float e = fexp2(dt * Al2[j][n]);
        H[j][n] = e * H[j][n] + dx;
        y += H[j][n];
      }
      float sz = bf2f(j == 0 ? zq.x : zq.y);
      bfu r = f2bf(y * sz);
      if (j == 0) oq.x = r; else oq.y = r;
    }
    *(ushort2*)(yz + base + (size_t)i * 768) = oq;
  }
}

extern "C" void kernel_launch(void* const* d_in, const int* in_sizes, int n_in,
                              void* d_out, int out_size, void* d_ws, size_t ws_size,
                              hipStream_t stream){
  const float* x     = (const float*)d_in[0];
  const float* W_in  = (const float*)d_in[1];
  const float* A_log = (const float*)d_in[2];
  const float* D_par = (const float*)d_in[3];
  const float* W_x   = (const float*)d_in[4];
  const float* W_dt  = (const float*)d_in[5];
  const float* b_dt  = (const float*)d_in[6];
  const float* W_out = (const float*)d_in[7];
  float* out = (float*)d_out;
  (void)in_sizes; (void)n_in; (void)out_size; (void)ws_size;

  char* base = (char*)d_ws;
  size_t off = 0;
  auto alloc = [&](size_t bytes)->char*{
    char* p = base + off; off += (bytes + 255) & ~(size_t)255; return p;
  };
  bfu*   x_bf  = (bfu*)  alloc((size_t)16384 * 512 * 2);
  bfu*   WinT  = (bfu*)  alloc((size_t)1536 * 512 * 2);
  bfu*   WoutT = (bfu*)  alloc((size_t)512 * 768 * 2);
  float* WxT   = (float*)alloc((size_t)8 * 768 * 4);
  bfu*   xssm  = (bfu*)  alloc((size_t)16384 * 768 * 2);
  bfu*   siluz = (bfu*)  alloc((size_t)16384 * 768 * 2);
  float* u     = (float*)alloc((size_t)16384 * 8 * 4);
  float* Pws   = (float*)alloc((size_t)8 * 64 * 768 * 8 * 4);
  float* Hws   = (float*)alloc((size_t)8 * 64 * 768 * 8 * 4);
  bfu*   yz    = (bfu*)  alloc((size_t)16384 * 768 * 2);

  // 1) fused conversions
  cvt_all_kernel<<<12824, 256, 0, stream>>>(x, x_bf, W_in, W_out, W_x, WinT, WoutT, WxT);
  // 2) GEMM1: grid = (16384/256)*(1536/128) = 64*12 = 768 blocks (2/CU resident)
  gemm_8p<0, 512><<<768, 256, 0, stream>>>(x_bf, WinT, xssm, siluz, 12, 1536);
  // 3) u = xssm @ W_x
  u_kernel<<<4096, 256, 0, stream>>>(xssm, WxT, u);
  // 4-6) chunked scan
  scan_phase1<<<1536, 128, 0, stream>>>(xssm, u, W_dt, b_dt, A_log, Pws, Hws);
  scan_phase2<<<192, 256, 0, stream>>>(Pws, Hws);
  scan_phase3<<<1536, 128, 0, stream>>>(xssm, u, W_dt, b_dt, A_log, D_par, siluz, Pws, yz);
  // 7) GEMM2: grid = (16384/256)*(512/128) = 64*4 = 256 blocks
  gemm_8p<1, 768><<<256, 256, 0, stream>>>(yz, WoutT, out, nullptr, 4, 512);
}

// Round 9
// 165.775 us; speedup vs baseline: 1.1734x; 1.1734x over previous
//
#include <hip/hip_runtime.h>

typedef unsigned short bfu;
typedef __attribute__((ext_vector_type(8))) short short8;
typedef __attribute__((ext_vector_type(4))) float f32x4;

__device__ __forceinline__ float bf2f(bfu u){
  union { unsigned int i; float f; } v; v.i = ((unsigned int)u) << 16; return v.f;
}
__device__ __forceinline__ bfu f2bf(float f){
  union { float f; unsigned int i; } v; v.f = f;
  unsigned int r = (v.i + 0x7FFFu + ((v.i >> 16) & 1u)) >> 16;
  return (bfu)r;
}
__device__ __forceinline__ float fexp2(float x){ return __builtin_amdgcn_exp2f(x); }
__device__ __forceinline__ float flog2(float x){ return __builtin_amdgcn_logf(x); }
__device__ __forceinline__ float softplusf(float x){
  float t = fexp2(-fabsf(x) * 1.44269504088896f);
  return fmaxf(x, 0.f) + 0.69314718055995f * flog2(1.f + t);
}
__device__ __forceinline__ void gload16(const bfu* g, bfu* l){
  __builtin_amdgcn_global_load_lds((const __attribute__((address_space(1))) unsigned int*)g,
                                   (__attribute__((address_space(3))) unsigned int*)l, 16, 0, 0);
}

// ---------------- fused conversion kernel ----------------
__global__ __launch_bounds__(256) void cvt_all_kernel(const float* __restrict__ x, bfu* __restrict__ x_bf,
                                                      const float* __restrict__ W_in, const float* __restrict__ W_out,
                                                      const float* __restrict__ W_x,
                                                      bfu* __restrict__ WinT, bfu* __restrict__ WoutT,
                                                      float* __restrict__ WxT){
  int g = blockIdx.x * 256 + threadIdx.x;
  if (g < 2097152){
    float4 v = ((const float4*)x)[g];
    ushort4 o;
    o.x = f2bf(v.x); o.y = f2bf(v.y); o.z = f2bf(v.z); o.w = f2bf(v.w);
    ((ushort4*)x_bf)[g] = o;
    return;
  }
  int h = g - 2097152;
  if (h < 786432){
    int r = h % 512, c = h / 512;
    WinT[h] = f2bf(W_in[(size_t)r * 1536 + c]);
  } else if (h < 786432 + 393216){
    int h2 = h - 786432;
    int r = h2 % 768, c = h2 / 768;
    WoutT[h2] = f2bf(W_out[(size_t)r * 512 + c]);
  } else if (h < 786432 + 393216 + 6144){
    int h2 = h - (786432 + 393216);
    int n = h2 / 768, k = h2 % 768;
    WxT[h2] = W_x[(size_t)k * 8 + n];
  }
}

// ---------------- MFMA GEMM: C = A(MxK) * Bt(NxK)^T ----------------
// BM=256, BN=128, BK=64, 512 thr (8 waves: 4M x 2N, 64x64/wave).
// Minimum-2-phase loop (T3 recipe): double-buffered LDS (2 x 48KB);
// per K-tile: STAGE(t+1) ISSUED FIRST -> ds_read(t) -> setprio MFMA ->
// vmcnt(0) [hidden under the compute] -> ONE barrier -> swap.
// T1 XCD swizzle; T2 LDS swizzle via pre-swizzled global source; T5 setprio.
template<int EPI, int KK>
__global__ __launch_bounds__(512)
void gemm_2p(const bfu* __restrict__ Amat, const bfu* __restrict__ Bt,
             void* __restrict__ out0, void* __restrict__ out1,
             int NBN, int N)
{
  constexpr int NT = KK / 64;
  // per buf: A 256x64 (16384 elems) + B 128x64 (8192 elems) = 24576 elems (48KB)
  __shared__ bfu LDS[2 * 24576];
  const int tid  = threadIdx.x;
  const int lane = tid & 63;
  const int w    = tid >> 6;
  const int wr   = w >> 1, wc = w & 1;   // 4M x 2N wave grid

  // T1: XCD-aware bijective swizzle (grid % 8 == 0)
  const int cpx = gridDim.x >> 3;
  const int id  = blockIdx.x;
  const int nid = (id & 7) * cpx + (id >> 3);
  const int bn  = nid % NBN;
  const int bm  = nid / NBN;

  // staging: set covers 64 rows; thread t -> row (t>>3), 16B slot (t&7)
  const int srow = tid >> 3;                       // 0..63
  const int scol = ((tid & 7) ^ (srow & 7)) * 8;   // pre-swizzled global col (T2)
  const bfu* gA = Amat + ((size_t)(bm * 256 + srow)) * KK + scol;
  const bfu* gB = Bt   + ((size_t)(bn * 128 + srow)) * KK + scol;

  // stage tile t into buffer buf: A 4 sets, B 2 sets (6 gloads/thread)
  auto STAGE = [&](int t, int buf){
    const int k0 = t * 64;
    bfu* dst = (bfu*)LDS + buf * 24576 + tid * 8;
    #pragma unroll
    for (int i = 0; i < 4; i++)
      gload16(gA + (size_t)(i * 64) * KK + k0, dst + i * 4096);
    #pragma unroll
    for (int j = 0; j < 2; j++)
      gload16(gB + (size_t)(j * 64) * KK + k0, dst + 16384 + j * 4096);
  };

  f32x4 acc[4][4];
  #pragma unroll
  for (int i = 0; i < 4; i++)
    #pragma unroll
    for (int j = 0; j < 4; j++)
      #pragma unroll
      for (int r = 0; r < 4; r++) acc[i][j][r] = 0.f;

  // prologue: stage tile 0, drain once, barrier
  STAGE(0, 0);
  asm volatile("s_waitcnt vmcnt(0)" ::: "memory");
  __builtin_amdgcn_s_barrier();

  int cur = 0;
  for (int t = 0; t < NT; ++t){
    // 1) issue next tile's loads FIRST (into the buffer nobody reads this iter)
    if (t + 1 < NT) STAGE(t + 1, cur ^ 1);

    // 2) compute current tile from resident buffer
    const bfu* Ab = (const bfu*)LDS + cur * 24576;
    const bfu* Bb = Ab + 16384;
    #pragma unroll
    for (int kk = 0; kk < 2; kk++){
      short8 a[4], b[4];
      const int sA = ((kk * 4 + (lane >> 4)) ^ (lane & 7)) * 8;
      #pragma unroll
      for (int m = 0; m < 4; m++){
        int r = wr * 64 + m * 16 + (lane & 15);
        a[m] = *(const short8*)&Ab[r * 64 + sA];
      }
      #pragma unroll
      for (int n = 0; n < 4; n++){
        int r = wc * 64 + n * 16 + (lane & 15);
        b[n] = *(const short8*)&Bb[r * 64 + sA];
      }
      __builtin_amdgcn_s_setprio(1);
      #pragma unroll
      for (int m = 0; m < 4; m++)
        #pragma unroll
        for (int n = 0; n < 4; n++)
          acc[m][n] = __builtin_amdgcn_mfma_f32_16x16x32_bf16(a[m], b[n], acc[m][n], 0, 0, 0);
      __builtin_amdgcn_s_setprio(0);
    }

    // 3) next tile's loads have had the whole compute phase to land
    if (t + 1 < NT){
      asm volatile("s_waitcnt vmcnt(0)" ::: "memory");
      __builtin_amdgcn_s_barrier();   // also fences ds_reads of cur before restage
      cur ^= 1;
    }
  }

  // ---- epilogue (r5-proven mapping)
  #pragma unroll
  for (int m = 0; m < 4; m++){
    #pragma unroll
    for (int n = 0; n < 4; n++){
      const int row0 = bm * 256 + wr * 64 + m * 16 + (lane >> 4) * 4;
      const int col  = bn * 128 + wc * 64 + n * 16 + (lane & 15);
      #pragma unroll
      for (int r = 0; r < 4; r++){
        float v = acc[m][n][r];
        int row = row0 + r;
        if (EPI == 0){
          float s = v / (1.f + __expf(-v));   // silu
          if (col < 768) ((bfu*)out0)[(size_t)row * 768 + col]         = f2bf(s);
          else           ((bfu*)out1)[(size_t)row * 768 + (col - 768)] = f2bf(s);
        } else {
          ((float*)out0)[(size_t)row * N + col] = v;
        }
      }
    }
  }
}

// ---------------- u = xssm @ W_x  (uses WxT [8][768], coalesced) ----------------
__global__ __launch_bounds__(256) void u_kernel(const bfu* __restrict__ xssm, const float* __restrict__ WxT,
                                                float* __restrict__ u){
  int wid = threadIdx.x >> 6, lane = threadIdx.x & 63;
  int row = blockIdx.x * 4 + wid;
  const bfu* xr = xssm + (size_t)row * 768;
  float acc[8];
  #pragma unroll
  for (int n = 0; n < 8; n++) acc[n] = 0.f;
  #pragma unroll
  for (int i = 0; i < 3; i++){
    int kb = i * 256 + lane * 4;
    ushort4 xq = *(const ushort4*)(xr + kb);
    float x0 = bf2f(xq.x), x1 = bf2f(xq.y), x2 = bf2f(xq.z), x3 = bf2f(xq.w);
    #pragma unroll
    for (int n = 0; n < 8; n++){
      float4 wv = *(const float4*)(WxT + (size_t)n * 768 + kb);
      acc[n] += x0 * wv.x + x1 * wv.y + x2 * wv.z + x3 * wv.w;
    }
  }
  #pragma unroll
  for (int n = 0; n < 8; n++){
    #pragma unroll
    for (int off = 32; off >= 1; off >>= 1) acc[n] += __shfl_xor(acc[n], off, 64);
  }
  if (lane == 0){
    float4 o0 = { acc[0], acc[1], acc[2], acc[3] };
    float4 o1 = { acc[4], acc[5], acc[6], acc[7] };
    *(float4*)(u + (size_t)row * 8)     = o0;
    *(float4*)(u + (size_t)row * 8 + 4) = o1;
  }
}

// ---------------- scan phase 1: per-chunk local scan, delta inline ----------------
__global__ __launch_bounds__(128) void scan_phase1(const bfu* __restrict__ xssm, const float* __restrict__ u,
    const float* __restrict__ Wdt, const float* __restrict__ bdt, const float* __restrict__ A_log,
    float* __restrict__ Pws, float* __restrict__ Hws){
  int tid = threadIdx.x;
  int bid = blockIdx.x;
  int b = bid / 192; int rem = bid % 192;
  int c = rem / 3;   int dblk = rem % 3;
  int d0 = dblk * 256 + tid * 2;
  float Al2[2][8], H[2][8], Wr[2][8], bd[2], S[2];
  #pragma unroll
  for (int j = 0; j < 2; j++){
    bd[j] = bdt[d0 + j];
    S[j] = 0.f;
    #pragma unroll
    for (int n = 0; n < 8; n++){
      Al2[j][n] = -__expf(A_log[(size_t)(d0 + j) * 8 + n]) * 1.4426950408889634f;
      Wr[j][n]  = Wdt[(size_t)n * 768 + d0 + j];
      H[j][n] = 0.f;
    }
  }
  int r0 = b * 2048 + c * 32;
  size_t base = (size_t)r0 * 768 + d0;
  #pragma unroll 8
  for (int i = 0; i < 32; i++){
    float4 u0 = *(const float4*)(u + (size_t)(r0 + i) * 8);
    float4 u1 = *(const float4*)(u + (size_t)(r0 + i) * 8 + 4);
    ushort2 xq = *(const ushort2*)(xssm + base + (size_t)i * 768);
    #pragma unroll
    for (int j = 0; j < 2; j++){
      float xt = bf2f(j == 0 ? xq.x : xq.y);
      float dv = bd[j] + u0.x * Wr[j][0] + u0.y * Wr[j][1] + u0.z * Wr[j][2] + u0.w * Wr[j][3]
                       + u1.x * Wr[j][4] + u1.y * Wr[j][5] + u1.z * Wr[j][6] + u1.w * Wr[j][7];
      float dt = softplusf(dv);
      float dx = dt * xt;
      S[j] += dt;
      #pragma unroll
      for (int n = 0; n < 8; n++){
        float e = fexp2(dt * Al2[j][n]);
        H[j][n] = e * H[j][n] + dx;
      }
    }
  }
  size_t o = (((size_t)b * 64 + c) * 768 + d0) * 8;
  #pragma unroll
  for (int j = 0; j < 2; j++){
    float4 p0, p1;
    p0.x = fexp2(S[j] * Al2[j][0]); p0.y = fexp2(S[j] * Al2[j][1]);
    p0.z = fexp2(S[j] * Al2[j][2]); p0.w = fexp2(S[j] * Al2[j][3]);
    p1.x = fexp2(S[j] * Al2[j][4]); p1.y = fexp2(S[j] * Al2[j][5]);
    p1.z = fexp2(S[j] * Al2[j][6]); p1.w = fexp2(S[j] * Al2[j][7]);
    float4 h0 = { H[j][0], H[j][1], H[j][2], H[j][3] };
    float4 h1 = { H[j][4], H[j][5], H[j][6], H[j][7] };
    *(float4*)(Pws + o + j * 8)     = p0;
    *(float4*)(Pws + o + j * 8 + 4) = p1;
    *(float4*)(Hws + o + j * 8)     = h0;
    *(float4*)(Hws + o + j * 8 + 4) = h1;
  }
}

// ---------------- scan phase 2: combine chunks; Hin written IN-PLACE into Pws ----------------
__global__ __launch_bounds__(256) void scan_phase2(float* __restrict__ Pws, const float* __restrict__ Hws){
  int g = blockIdx.x * 256 + threadIdx.x;   // 49152 = 8*768*8
  int within = g % 6144;                    // d*8+n
  int b = g / 6144;
  size_t base = (size_t)b * 64 * 6144 + within;
  float hin = 0.f;
  #pragma unroll 8
  for (int c = 0; c < 64; c++){
    size_t idx = base + (size_t)c * 6144;
    float p = Pws[idx], hh = Hws[idx];
    Pws[idx] = hin;                         // h_in for chunk c
    hin = p * hin + hh;
  }
}

// ---------------- scan phase 3: re-run chunk with h_in, delta inline, fuse gate ----------------
__global__ __launch_bounds__(128) void scan_phase3(const bfu* __restrict__ xssm, const float* __restrict__ u,
    const float* __restrict__ Wdt, const float* __restrict__ bdt, const float* __restrict__ A_log,
    const float* __restrict__ Dp, const bfu* __restrict__ siluz, const float* __restrict__ Hin,
    bfu* __restrict__ yz){
  int tid = threadIdx.x;
  int bid = blockIdx.x;
  int b = bid / 192; int rem = bid % 192;
  int c = rem / 3;   int dblk = rem % 3;
  int d0 = dblk * 256 + tid * 2;
  float Al2[2][8], H[2][8], Wr[2][8], bd[2], Dd[2];
  size_t o = (((size_t)b * 64 + c) * 768 + d0) * 8;
  #pragma unroll
  for (int j = 0; j < 2; j++){
    bd[j] = bdt[d0 + j];
    Dd[j] = Dp[d0 + j];
    float4 h0 = *(const float4*)(Hin + o + j * 8);
    float4 h1 = *(const float4*)(Hin + o + j * 8 + 4);
    H[j][0] = h0.x; H[j][1] = h0.y; H[j][2] = h0.z; H[j][3] = h0.w;
    H[j][4] = h1.x; H[j][5] = h1.y; H[j][6] = h1.z; H[j][7] = h1.w;
    #pragma unroll
    for (int n = 0; n < 8; n++){
      Al2[j][n] = -__expf(A_log[(size_t)(d0 + j) * 8 + n]) * 1.4426950408889634f;
      Wr[j][n]  = Wdt[(size_t)n * 768 + d0 + j];
    }
  }
  int r0 = b * 2048 + c * 32;
  size_t base = (size_t)r0 * 768 + d0;
  #pragma unroll 8
  for (int i = 0; i < 32; i++){
    float4 u0 = *(const float4*)(u + (size_t)(r0 + i) * 8);
    float4 u1 = *(const float4*)(u + (size_t)(r0 + i) * 8 + 4);
    ushort2 xq = *(const ushort2*)(xssm + base + (size_t)i * 768);
    ushort2 zq = *(const ushort2*)(siluz + base + (size_t)i * 768);
    ushort2 oq;
    #pragma unroll
    for (int j = 0; j < 2; j++){
      float xt = bf2f(j == 0 ? xq.x : xq.y);
      float dv = bd[j] + u0.x * Wr[j][0] + u0.y * Wr[j][1] + u0.z * Wr[j][2] + u0.w * Wr[j][3]
                       + u1.x * Wr[j][4] + u1.y * Wr[j][5] + u1.z * Wr[j][6] + u1.w * Wr[j][7];
      float dt = softplusf(dv);
      float dx = dt * xt;
      float y = Dd[j] * xt;
      #pragma unroll
      for (int n = 0; n < 8; n++){
        float e = fexp2(dt * Al2[j][n]);
        H[j][n] = e * H[j][n] + dx;
        y += H[j][n];
      }
      float sz = bf2f(j == 0 ? zq.x : zq.y);
      bfu r = f2bf(y * sz);
      if (j == 0) oq.x = r; else oq.y = r;
    }
    *(ushort2*)(yz + base + (size_t)i * 768) = oq;
  }
}

extern "C" void kernel_launch(void* const* d_in, const int* in_sizes, int n_in,
                              void* d_out, int out_size, void* d_ws, size_t ws_size,
                              hipStream_t stream){
  const float* x     = (const float*)d_in[0];
  const float* W_in  = (const float*)d_in[1];
  const float* A_log = (const float*)d_in[2];
  const float* D_par = (const float*)d_in[3];
  const float* W_x   = (const float*)d_in[4];
  const float* W_dt  = (const float*)d_in[5];
  const float* b_dt  = (const float*)d_in[6];
  const float* W_out = (const float*)d_in[7];
  float* out = (float*)d_out;
  (void)in_sizes; (void)n_in; (void)out_size; (void)ws_size;

  char* base = (char*)d_ws;
  size_t off = 0;
  auto alloc = [&](size_t bytes)->char*{
    char* p = base + off; off += (bytes + 255) & ~(size_t)255; return p;
  };
  bfu*   x_bf  = (bfu*)  alloc((size_t)16384 * 512 * 2);
  bfu*   WinT  = (bfu*)  alloc((size_t)1536 * 512 * 2);
  bfu*   WoutT = (bfu*)  alloc((size_t)512 * 768 * 2);
  float* WxT   = (float*)alloc((size_t)8 * 768 * 4);
  bfu*   xssm  = (bfu*)  alloc((size_t)16384 * 768 * 2);
  bfu*   siluz = (bfu*)  alloc((size_t)16384 * 768 * 2);
  float* u     = (float*)alloc((size_t)16384 * 8 * 4);
  float* Pws   = (float*)alloc((size_t)8 * 64 * 768 * 8 * 4);
  float* Hws   = (float*)alloc((size_t)8 * 64 * 768 * 8 * 4);
  bfu*   yz    = (bfu*)  alloc((size_t)16384 * 768 * 2);

  // 1) fused conversions
  cvt_all_kernel<<<12824, 256, 0, stream>>>(x, x_bf, W_in, W_out, W_x, WinT, WoutT, WxT);
  // 2) GEMM1: grid = (16384/256)*(1536/128) = 64*12 = 768 blocks
  gemm_2p<0, 512><<<768, 512, 0, stream>>>(x_bf, WinT, xssm, siluz, 12, 1536);
  // 3) u = xssm @ W_x
  u_kernel<<<4096, 256, 0, stream>>>(xssm, WxT, u);
  // 4-6) chunked scan
  scan_phase1<<<1536, 128, 0, stream>>>(xssm, u, W_dt, b_dt, A_log, Pws, Hws);
  scan_phase2<<<192, 256, 0, stream>>>(Pws, Hws);
  scan_phase3<<<1536, 128, 0, stream>>>(xssm, u, W_dt, b_dt, A_log, D_par, siluz, Pws, yz);
  // 7) GEMM2: grid = (16384/256)*(512/128) = 64*4 = 256 blocks
  gemm_2p<1, 768><<<256, 512, 0, stream>>>(yz, WoutT, out, nullptr, 4, 512);
}